// Round 6
// baseline (586.409 us; speedup 1.0000x reference)
//
#include <hip/hip_runtime.h>
#include <stdint.h>

// Persistent-kernel LSTM NAS controller rollout — fence-free tagged dataflow,
// wave0-only batched polling, static x-projection tables.
// Cross-WG data = 8B relaxed AGENT atomics (tag<<32)|f32bits at MALL; no
// wbl2/inv fences. Per WG only wave 0 polls (8 cells/lane in flight) and
// stages to LDS -> 8x less poll traffic than r5 (A/B on hop-contention).
// Critical-path compute stripped: W_ih*emb[op] precomputed (static), aw1 row
// computed in prior step's tail, ghh in hop-B shadow, opfc in LDS.
// 64 wgs x 512 thr; one hidden unit per wave; weights register-stationary
// (launch_bounds(512,2) -> 256 VGPR cap, no spill).
// RNG: JAX threefry2x32 partitionable (verified bit-exact rounds 2-5).

#define KWG    64
#define NTH    512
#define LSTEPS 32
#define DDIM   512
#define NOPS   16
#define NEGC   (-1.0e9f)

// ---------------- threefry2x32 core ----------------
static __device__ __forceinline__ void tf2x32(uint32_t k0, uint32_t k1,
                                              uint32_t c0, uint32_t c1,
                                              uint32_t& o0, uint32_t& o1){
  uint32_t ks2 = k0 ^ k1 ^ 0x1BD11BDAu;
  uint32_t x0 = c0 + k0;
  uint32_t x1 = c1 + k1;
#define TFR(r) { x0 += x1; x1 = (x1 << (r)) | (x1 >> (32 - (r))); x1 ^= x0; }
  TFR(13) TFR(15) TFR(26) TFR(6)
  x0 += k1;  x1 += ks2 + 1u;
  TFR(17) TFR(29) TFR(16) TFR(24)
  x0 += ks2; x1 += k0 + 2u;
  TFR(13) TFR(15) TFR(26) TFR(6)
  x0 += k0;  x1 += k1 + 3u;
  TFR(17) TFR(29) TFR(16) TFR(24)
  x0 += k1;  x1 += ks2 + 4u;
  TFR(13) TFR(15) TFR(26) TFR(6)
  x0 += ks2; x1 += k0 + 5u;
#undef TFR
  o0 = x0; o1 = x1;
}

static __device__ __forceinline__ float gumbel_bits(uint32_t bits){
  float f = __uint_as_float((bits >> 9) | 0x3f800000u) - 1.0f;
  float u = (f == 0.0f) ? 1.1754943508222875e-38f : f;
  return -logf(-logf(u));
}

static __device__ __forceinline__ float sigm(float x){
  return 1.0f / (1.0f + expf(-x));
}

static __device__ __forceinline__ float wredsum(float v){
  #pragma unroll
  for (int m = 32; m; m >>= 1) v += __shfl_xor(v, m, 64);
  return v;
}

// gather 8 elems at stride 64: d = 64k + lane  (global or LDS)
static __device__ __forceinline__ void gl8(const float* __restrict__ p, int lane, float* r){
  #pragma unroll
  for (int k = 0; k < 8; ++k) r[k] = p[(k << 6) + lane];
}

static __device__ __forceinline__ float dot8(const float* w, const float* x){
  float s = 0.f;
  #pragma unroll
  for (int k = 0; k < 8; ++k) s += w[k]*x[k];
  return s;
}

// ---------------- tagged-atomic helpers ----------------
static __device__ __forceinline__ uint64_t tpack(uint32_t tag, float f){
  return ((uint64_t)tag << 32) | (uint64_t)__float_as_uint(f);
}
static __device__ __forceinline__ uint64_t ald64(const uint64_t* p){
  return __hip_atomic_load(p, __ATOMIC_RELAXED, __HIP_MEMORY_SCOPE_AGENT);
}
static __device__ __forceinline__ void ast64(uint64_t* p, uint64_t v){
  __hip_atomic_store(p, v, __ATOMIC_RELAXED, __HIP_MEMORY_SCOPE_AGENT);
}
// poll 8 cells (d=64k+lane) into registers (aw1 register rows)
static __device__ __forceinline__ void poll8s(const uint64_t* base, int lane,
                                              uint32_t tag, float* r){
  uint64_t v[8];
  for (;;){
    #pragma unroll
    for (int k = 0; k < 8; ++k) v[k] = ald64(base + (k << 6) + lane);
    bool ok = true;
    #pragma unroll
    for (int k = 0; k < 8; ++k) ok &= ((uint32_t)(v[k] >> 32) == tag);
    if (ok) break;
    __builtin_amdgcn_s_sleep(1);
  }
  #pragma unroll
  for (int k = 0; k < 8; ++k) r[k] = __uint_as_float((uint32_t)v[k]);
}
// wave0 batch-poll of one 512-vector into LDS (8 cells/lane in flight)
static __device__ __forceinline__ void wpoll512(const uint64_t* base, uint32_t tag,
                                                float* dst, int lane){
  uint64_t v[8];
  for (;;){
    #pragma unroll
    for (int k = 0; k < 8; ++k) v[k] = ald64(base + (k << 6) + lane);
    bool ok = true;
    #pragma unroll
    for (int k = 0; k < 8; ++k) ok &= ((uint32_t)(v[k] >> 32) == tag);
    if (ok) break;
    __builtin_amdgcn_s_sleep(1);
  }
  #pragma unroll
  for (int k = 0; k < 8; ++k) dst[(k << 6) + lane] = __uint_as_float((uint32_t)v[k]);
}

__global__ void __launch_bounds__(NTH, 2)
Controller_60601988547087_kernel(const float* __restrict__ emb,
                                 const float* __restrict__ wih,
                                 const float* __restrict__ whh,
                                 const float* __restrict__ bih,
                                 const float* __restrict__ bhh,
                                 const float* __restrict__ wa1,
                                 const float* __restrict__ wa2,
                                 const float* __restrict__ idxfc,
                                 const float* __restrict__ opfc,
                                 float* __restrict__ out,
                                 uint64_t* __restrict__ ws64)
{
  const int tid  = threadIdx.x;
  const int wg   = blockIdx.x;
  const int wave = tid >> 6;              // 0..7
  const int lane = tid & 63;
  const int unit = (wg << 3) | wave;      // one hidden unit per wave, 512 total

  // workspace (u64 tagged cells)
  uint64_t* bufA64 = ws64;                          // h1      [512]
  uint64_t* bufB64 = ws64 + 512;                    // h2      [512]
  uint64_t* hw2g64 = ws64 + 1024;                   // W2.h1   [512]
  uint64_t* aw1g64 = ws64 + 1536;                   // aw1 rows[32][512], row r tag (r?4r:1)
  uint64_t* anch64 = ws64 + 1536 + 32*512;          // anchors [32][512], row r tag 4r (row0 unused)

  __shared__ float s_hc[DDIM];            // carry h / h2 staging
  __shared__ float s_h1[DDIM];            // h after cell1
  __shared__ float s_hw2[DDIM];           // h1 @ w_attn_2^T
  __shared__ float s_arow[DDIM];          // anchors[ni]
  __shared__ float s_xproj[17 * 32];      // [op][wave][gate] static W_ih·emb[op]
  __shared__ float s_opfc[NOPS * DDIM];   // 32 KB op_fc
  __shared__ float s_logits[33];
  __shared__ float s_oplog[16];
  __shared__ int   s_ibc[2];

  // ---- weights register-stationary, gathered at d = 64k+lane ----
  float wihr[4][8], whhr[4][8], a1r[8], a2r[8], fcr[8], bsum[4];
  #pragma unroll
  for (int g = 0; g < 4; ++g){
    gl8(wih + (size_t)((g << 9) + unit) * DDIM, lane, wihr[g]);
    gl8(whh + (size_t)((g << 9) + unit) * DDIM, lane, whhr[g]);
    bsum[g] = bih[(g << 9) + unit] + bhh[(g << 9) + unit];
  }
  gl8(wa1 + (size_t)unit * DDIM, lane, a1r);
  gl8(wa2 + (size_t)unit * DDIM, lane, a2r);
  gl8(idxfc, lane, fcr);

  for (int i = tid; i < NOPS * DDIM; i += NTH) s_opfc[i] = opfc[i];

  // ---- static x-projections: s_xproj[op][wave][g] = (W_ih · emb[op])[unit] ----
  for (int op = 0; op <= NOPS; ++op){
    float xc[8];
    gl8(emb + (size_t)op * DDIM, lane, xc);
    #pragma unroll
    for (int g = 0; g < 4; ++g){
      float xp = wredsum(dot8(wihr[g], xc));
      if (lane == 0) s_xproj[op * 32 + (wave << 2) + g] = xp;
    }
  }
  __syncthreads();

  // per-wave register cache of aw1 rows (row r owned by wave r&7, slot r>>3)
  float row0[8], row1[8], row2[8], row3[8];

  // ---- init: h0 = cell(emb[16],0,0) via xproj; publish tag 1 ----
  float cst;
  {
    const float* xp = s_xproj + 16 * 32 + (wave << 2);
    float gi = sigm(xp[0] + bsum[0]);
    float go = sigm(xp[3] + bsum[3]);
    cst = gi * tanhf(xp[2] + bsum[2]);   // c=0: forget term vanishes exactly
    float h0 = go * tanhf(cst);
    if (lane == 0) ast64(bufB64 + unit, tpack(1u, h0));
  }
  if (wave == 0) wpoll512(bufB64, 1u, s_hc, lane);
  __syncthreads();
  // aw1 row 0 = W1 · h0, publish tag 1; owner (wave0) caches slot0
  {
    float hcv[8];
    gl8(s_hc, lane, hcv);
    float pa = wredsum(dot8(a1r, hcv));
    if (lane == 0) ast64(aw1g64 + unit, tpack(1u, pa));
  }
  if (wave == 0) poll8s(aw1g64, lane, 1u, row0);

  uint32_t key0 = 0u, key1v = 42u;       // jax.random.key(42) -> (0, 42)
  float ent_sum = 0.f, lp_sum = 0.f;
  int prev_op = NOPS;                    // inp0 = embedding[16]

  for (int t = 0; t < LSTEPS; ++t){
    const uint32_t tagA = 4u*(uint32_t)t + 2u;
    const uint32_t tagB = 4u*(uint32_t)t + 3u;
    const uint32_t tagC = 4u*(uint32_t)t + 4u;

    // ========== Stage A: cell1 = xproj[prev_op] + W_hh·h_carry ==========
    {
      float hcv[8];
      gl8(s_hc, lane, hcv);
      const float* xp = s_xproj + prev_op * 32 + (wave << 2);
      float p0 = wredsum(dot8(whhr[0], hcv));
      float p1 = wredsum(dot8(whhr[1], hcv));
      float p2 = wredsum(dot8(whhr[2], hcv));
      float p3 = wredsum(dot8(whhr[3], hcv));
      float gi = sigm(xp[0] + p0 + bsum[0]);
      float gf = sigm(xp[1] + p1 + bsum[1]);
      float go = sigm(xp[3] + p3 + bsum[3]);
      cst = gf * cst + gi * tanhf(xp[2] + p2 + bsum[2]);
      float hn = go * tanhf(cst);
      if (lane == 0) ast64(bufA64 + unit, tpack(tagA, hn));
    }
    // shadow: owner wave stale-polls aw1 row t (published at tail of step t-1)
    if (t > 0 && wave == (t & 7)){
      const uint64_t* rb = aw1g64 + (size_t)t * DDIM;
      uint32_t rtag = 4u * (uint32_t)t;
      int slot = t >> 3;
      if      (slot == 0) poll8s(rb, lane, rtag, row0);
      else if (slot == 1) poll8s(rb, lane, rtag, row1);
      else if (slot == 2) poll8s(rb, lane, rtag, row2);
      else                poll8s(rb, lane, rtag, row3);
    }
    if (wave == 0) wpoll512(bufA64, tagA, s_h1, lane);   // hop A
    __syncthreads();

    // ========== Stage B: publish hw2 slice; ghh in hop-B shadow ==========
    float ghh0, ghh1, ghh2, ghh3;
    float h1c[8];
    gl8(s_h1, lane, h1c);
    {
      float q = wredsum(dot8(a2r, h1c));
      if (lane == 0) ast64(hw2g64 + unit, tpack(tagB, q));
    }
    if (wave != 0){
      ghh0 = wredsum(dot8(whhr[0], h1c));
      ghh1 = wredsum(dot8(whhr[1], h1c));
      ghh2 = wredsum(dot8(whhr[2], h1c));
      ghh3 = wredsum(dot8(whhr[3], h1c));
    } else {
      wpoll512(hw2g64, tagB, s_hw2, lane);               // hop B
    }
    __syncthreads();
    if (wave == 0){
      ghh0 = wredsum(dot8(whhr[0], h1c));
      ghh1 = wredsum(dot8(whhr[1], h1c));
      ghh2 = wredsum(dot8(whhr[2], h1c));
      ghh3 = wredsum(dot8(whhr[3], h1c));
    }

    // ======== Node logits + sampling — EVERY WG, bit-identical ========
    int ni;
    float nlp_s = 0.f, nent_s = 0.f;
    uint32_t k2a_s = 0u, k2b_s = 0u;
    {
      float h2c[8];
      gl8(s_hw2, lane, h2c);
#define ROWDOT(RR, I)                                                          \
      { int i_ = (I);                                                          \
        if (i_ <= t){                                                          \
          float acc = 0.f;                                                     \
          _Pragma("unroll")                                                    \
          for (int k = 0; k < 8; ++k) acc += tanhf(RR[k] + h2c[k]) * fcr[k];   \
          acc = wredsum(acc);                                                  \
          if (lane == 0) s_logits[i_] = 2.5f * tanhf(acc / 5.0f);              \
        } }
      ROWDOT(row0, wave)
      ROWDOT(row1, wave + 8)
      ROWDOT(row2, wave + 16)
      ROWDOT(row3, wave + 24)
#undef ROWDOT
      __syncthreads();
      if (wave == 0){
        // split(key,3), partitionable/foldlike: row i = tf(key, (0, i))
        uint32_t s0 = 0, s1 = 0;
        if (lane < 3) tf2x32(key0, key1v, 0u, (uint32_t)lane, s0, s1);
        uint32_t k1a = __shfl(s0, 0, 64), k1b = __shfl(s1, 0, 64);
        k2a_s = __shfl(s0, 1, 64); k2b_s = __shfl(s1, 1, 64);
        uint32_t nk0 = __shfl(s0, 2, 64), nk1 = __shfl(s1, 2, 64);
        key0 = nk0; key1v = nk1;
        // 33 random bits: bits[i] = x0 ^ x1 of tf(k1, (0, i))
        uint32_t y0 = 0, y1 = 0;
        if (lane < 33) tf2x32(k1a, k1b, 0u, (uint32_t)lane, y0, y1);
        uint32_t bits = y0 ^ y1;
        float gmb   = gumbel_bits(bits);
        float logit = (lane < 33) ? ((lane <= t) ? s_logits[lane] : NEGC) : -3.0e38f;
        float cand  = (lane < 33) ? (logit + gmb) : -3.0e38f;
        float v = cand; int bi = lane;
        #pragma unroll
        for (int m = 32; m; m >>= 1){
          float ov = __shfl_xor(v, m, 64); int ob = __shfl_xor(bi, m, 64);
          if (ov > v || (ov == v && ob < bi)){ v = ov; bi = ob; }
        }
        int ni_ = bi;
        float lm = (lane < 33) ? logit : -3.0e38f;
        #pragma unroll
        for (int m = 32; m; m >>= 1) lm = fmaxf(lm, __shfl_xor(lm, m, 64));
        float ex   = (lane < 33) ? expf(logit - lm) : 0.f;
        float ssum = wredsum(ex);
        float lsm  = logit - lm - logf(ssum);
        nlp_s  = -__shfl(lsm, ni_, 64);
        float entc = (lane <= t) ? (-lsm * expf(lsm)) : 0.f;
        nent_s = wredsum(entc);
        if (lane == 0) s_ibc[0] = ni_;
      }
      __syncthreads();
      ni = s_ibc[0];
    }

    // ========== Stage C: cell2 (op_in = anchors[ni]) ==========
    if (wave == 0){
      if (ni > 0) wpoll512(anch64 + (size_t)ni * DDIM, 4u * (uint32_t)ni, s_arow, lane);
      else {
        #pragma unroll
        for (int k = 0; k < 8; ++k) s_arow[(k << 6) + lane] = 0.f;
      }
    }
    __syncthreads();
    {
      float oc8[8];
      gl8(s_arow, lane, oc8);
      float q0 = wredsum(dot8(wihr[0], oc8));
      float q1 = wredsum(dot8(wihr[1], oc8));
      float q2 = wredsum(dot8(wihr[2], oc8));
      float q3 = wredsum(dot8(wihr[3], oc8));
      float gi = sigm(q0 + ghh0 + bsum[0]);
      float gf = sigm(q1 + ghh1 + bsum[1]);
      float go = sigm(q3 + ghh3 + bsum[3]);
      cst = gf * cst + gi * tanhf(q2 + ghh2 + bsum[2]);
      float hn = go * tanhf(cst);
      if (lane == 0){
        ast64(bufB64 + unit, tpack(tagC, hn));
        if (t < LSTEPS - 1)
          ast64(anch64 + (size_t)(t + 1) * DDIM + unit, tpack(tagC, hn));
      }
    }
    if (wave == 0) wpoll512(bufB64, tagC, s_hc, lane);    // hop C
    __syncthreads();

    // ========== Tail: aw1 row t+1 publish + op logits + sample ==========
    {
      float hc2[8];
      gl8(s_hc, lane, hc2);
      if (t < LSTEPS - 1){
        float pa = wredsum(dot8(a1r, hc2));               // W1·h2 = aw1[t+1]
        if (lane == 0) ast64(aw1g64 + (size_t)(t + 1) * DDIM + unit, tpack(tagC, pa));
      }
      #pragma unroll
      for (int jj = 0; jj < 2; ++jj){
        int i = wave + (jj << 3);
        float acc = 0.f;
        #pragma unroll
        for (int k = 0; k < 8; ++k) acc += s_opfc[i * DDIM + (k << 6) + lane] * hc2[k];
        acc = wredsum(acc);
        if (lane == 0) s_oplog[i] = tanhf(acc / 5.0f);    // (2.5/2.5)=1 scale
      }
      __syncthreads();
    }
    int oi;
    {
      if (wave == 0){
        // 16 random bits: bits[i] = x0 ^ x1 of tf(k2, (0, i))
        uint32_t z0 = 0, z1 = 0;
        if (lane < 16) tf2x32(k2a_s, k2b_s, 0u, (uint32_t)lane, z0, z1);
        uint32_t bits = z0 ^ z1;
        float gmb   = gumbel_bits(bits);
        float logit = (lane < 16) ? s_oplog[lane] : -3.0e38f;
        float cand  = (lane < 16) ? (logit + gmb) : -3.0e38f;
        float v = cand; int bi = lane;
        #pragma unroll
        for (int m = 32; m; m >>= 1){
          float ov = __shfl_xor(v, m, 64); int ob = __shfl_xor(bi, m, 64);
          if (ov > v || (ov == v && ob < bi)){ v = ov; bi = ob; }
        }
        int oi_ = bi;
        float lm = (lane < 16) ? logit : -3.0e38f;
        #pragma unroll
        for (int m = 32; m; m >>= 1) lm = fmaxf(lm, __shfl_xor(lm, m, 64));
        float ex   = (lane < 16) ? expf(logit - lm) : 0.f;
        float ssum = wredsum(ex);
        float olsm = logit - lm - logf(ssum);
        float olp  = -__shfl(olsm, oi_, 64);
        float oent = wredsum((lane < 16) ? (-olsm * expf(olsm)) : 0.f);
        lp_sum  += nlp_s + olp;
        ent_sum += nent_s + oent;
        if (lane == 0){
          s_ibc[1] = oi_;
          if (wg == 0){
            out[2 * t]     = (float)ni;
            out[2 * t + 1] = (float)oi_;
          }
        }
      }
      __syncthreads();
      oi = s_ibc[1];
    }
    prev_op = oi;
  }

  if (wg == 0 && wave == 0 && lane == 0){
    out[64] = ent_sum;
    out[65] = lp_sum;
  }
}

extern "C" void kernel_launch(void* const* d_in, const int* in_sizes, int n_in,
                              void* d_out, int out_size, void* d_ws, size_t ws_size,
                              hipStream_t stream) {
  (void)in_sizes; (void)n_in; (void)out_size; (void)ws_size;
  const float* emb  = (const float*)d_in[0];
  const float* wih  = (const float*)d_in[1];
  const float* whh  = (const float*)d_in[2];
  const float* bih  = (const float*)d_in[3];
  const float* bhh  = (const float*)d_in[4];
  const float* wa1  = (const float*)d_in[5];
  const float* wa2  = (const float*)d_in[6];
  const float* ifc  = (const float*)d_in[7];
  const float* ofc  = (const float*)d_in[8];
  float* out = (float*)d_out;
  uint64_t* ws = (uint64_t*)d_ws;
  hipLaunchKernelGGL(Controller_60601988547087_kernel,
                     dim3(KWG), dim3(NTH), 0, stream,
                     emb, wih, whh, bih, bhh, wa1, wa2, ifc, ofc, out, ws);
}